// Round 7
// baseline (653.428 us; speedup 1.0000x reference)
//
#include <hip/hip_runtime.h>
#include <math.h>

#define TOPK 8
#define NE   128
#define MARGIN 4e-5f

typedef _Float16 h8 __attribute__((ext_vector_type(8)));
typedef _Float16 h4 __attribute__((ext_vector_type(4)));
typedef float    f4 __attribute__((ext_vector_type(4)));

// byte address within a [row][64 halfs] LDS array (128 B row stride),
// XOR-swizzled so 16-lane column reads spread across all banks.
__device__ __forceinline__ int swz(int row, int kb) {
  return row * 128 + (kb ^ ((row & 7) << 4));
}

// ---------------- Kernel 0: split W into fp16 hi + scaled lo ----------------
__global__ __launch_bounds__(256) void router_wsplit(
    const float* __restrict__ W, _Float16* __restrict__ whi,
    _Float16* __restrict__ wlo, int n4) {
  const int i = blockIdx.x * 256 + threadIdx.x;
  if (i < n4) {
    const float4 v = ((const float4*)W)[i];
    h4 hi, lo;
#pragma unroll
    for (int q = 0; q < 4; ++q) {
      const float vq = ((const float*)&v)[q];
      const _Float16 h = (_Float16)vq;
      hi[q] = h;
      lo[q] = (_Float16)((vq - (float)h) * 2048.0f);  // lo' = lo * 2^11
    }
    ((h4*)whi)[i] = hi;
    ((h4*)wlo)[i] = lo;
  }
}

// ---------------- Pass 1: split-fp16 MFMA GEMM + sigmoid + top-8 + flag ----------------
// 256 threads = 4 waves; block tile 64 tokens x 128 experts; BK=64.
// Wave tile 32 tok x 64 exp: acc1 (hi*hi) + acc2 (cross terms, scale 2^11).
__global__ __launch_bounds__(256, 2) void router_pass1(
    const float* __restrict__ x,        // [T, H] fp32
    const _Float16* __restrict__ whi,   // [E, H] fp16
    const _Float16* __restrict__ wlo,   // [E, H] fp16 (x 2^11)
    const float* __restrict__ bias,
    float* __restrict__ out_w, float* __restrict__ out_i,
    unsigned int* __restrict__ mask, int T, int H) {
  __shared__ char lds[49152];
  // a_hi @0 (8KB: 64 rows x 128B), a_lo @8192, b_hi @16384 (16KB: 128 rows), b_lo @32768
  // epilogue reuse: logits fp32 [64][132] @0 (33.8 KB)

  const int tid = threadIdx.x;
  const int t0  = blockIdx.x * 64;
  const int l   = tid & 63;
  const int wv  = tid >> 6;
  const int wm  = wv & 1;              // token half (32)
  const int wn  = wv >> 1;             // expert half (64)

  const int xtok = tid >> 2, xc4 = tid & 3;     // x staging: row, col-group
  const int we   = tid & 127, wh = tid >> 7;    // W staging: row, chunk-half

  const float*    xbase  = x   + (size_t)(t0 + xtok) * H + xc4 * 4;
  const _Float16* whbase = whi + (size_t)we * H + wh * 32;
  const _Float16* wlbase = wlo + (size_t)we * H + wh * 32;

  f4 acc1[2][4], acc2[2][4];
#pragma unroll
  for (int mt = 0; mt < 2; ++mt)
#pragma unroll
    for (int nt = 0; nt < 4; ++nt) {
      acc1[mt][nt] = (f4)0.0f;
      acc2[mt][nt] = (f4)0.0f;
    }

  float4 px[4]; uint4 pwh[4], pwl[4];
#pragma unroll
  for (int j = 0; j < 4; ++j) {
    px[j]  = *(const float4*)(xbase + j * 16);
    pwh[j] = *(const uint4*)(whbase + j * 8);
    pwl[j] = *(const uint4*)(wlbase + j * 8);
  }

  for (int k0 = 0; k0 < H; k0 += 64) {
    __syncthreads();                   // previous tile's LDS reads done
    // ---- write staged tile to LDS (x converted to hi/lo fp16) ----
#pragma unroll
    for (int j = 0; j < 4; ++j) {
      const float4 v = px[j];
      h4 hi, lo;
#pragma unroll
      for (int q = 0; q < 4; ++q) {
        const float vq = ((const float*)&v)[q];
        const _Float16 h = (_Float16)vq;
        hi[q] = h;
        lo[q] = (_Float16)((vq - (float)h) * 2048.0f);
      }
      const int kb = xc4 * 8 + j * 32;         // byte col in A row
      *(h4*)(lds +        swz(xtok, kb)) = hi;
      *(h4*)(lds + 8192 + swz(xtok, kb)) = lo;
      const int kwb = wh * 64 + j * 16;        // byte col in B row
      *(uint4*)(lds + 16384 + swz(we, kwb)) = pwh[j];
      *(uint4*)(lds + 32768 + swz(we, kwb)) = pwl[j];
    }
    __syncthreads();

    // ---- prefetch next tile (hides under MFMA) ----
    if (k0 + 64 < H) {
#pragma unroll
      for (int j = 0; j < 4; ++j) {
        px[j]  = *(const float4*)(xbase + k0 + 64 + j * 16);
        pwh[j] = *(const uint4*)(whbase + k0 + 64 + j * 8);
        pwl[j] = *(const uint4*)(wlbase + k0 + 64 + j * 8);
      }
    }

    // ---- MFMA over two K=32 steps ----
#pragma unroll
    for (int ks = 0; ks < 2; ++ks) {
      const int kb = ks * 64 + ((l >> 4) * 16);  // this lane's 8-half K-slice (bytes)
      h8 Ah[2], Al[2];
#pragma unroll
      for (int mt = 0; mt < 2; ++mt) {
        const int row = wm * 32 + mt * 16 + (l & 15);
        Ah[mt] = *(const h8*)(lds +        swz(row, kb));
        Al[mt] = *(const h8*)(lds + 8192 + swz(row, kb));
      }
#pragma unroll
      for (int nt = 0; nt < 4; ++nt) {
        const int er = wn * 64 + nt * 16 + (l & 15);
        const h8 Bh = *(const h8*)(lds + 16384 + swz(er, kb));
        const h8 Bl = *(const h8*)(lds + 32768 + swz(er, kb));
#pragma unroll
        for (int mt = 0; mt < 2; ++mt) {
          acc1[mt][nt] = __builtin_amdgcn_mfma_f32_16x16x32_f16(Ah[mt], Bh, acc1[mt][nt], 0, 0, 0);
          acc2[mt][nt] = __builtin_amdgcn_mfma_f32_16x16x32_f16(Ah[mt], Bl, acc2[mt][nt], 0, 0, 0);
          acc2[mt][nt] = __builtin_amdgcn_mfma_f32_16x16x32_f16(Al[mt], Bh, acc2[mt][nt], 0, 0, 0);
        }
      }
    }
  }

  // ---- dump logits to LDS (C/D layout: col=lane&15, row=(lane>>4)*4+r) ----
  __syncthreads();
  float* logits = (float*)lds;
#pragma unroll
  for (int mt = 0; mt < 2; ++mt)
#pragma unroll
    for (int nt = 0; nt < 4; ++nt)
#pragma unroll
      for (int r = 0; r < 4; ++r) {
        const int row = wm * 32 + mt * 16 + (l >> 4) * 4 + r;
        const int col = wn * 64 + nt * 16 + (l & 15);
        logits[row * 132 + col] = acc1[mt][nt][r] + acc2[mt][nt][r] * (1.0f / 2048.0f);
      }
  __syncthreads();

  // ---- epilogue: sigmoid, top-8 across 16-lane groups, flag near-ties ----
  const int tx    = tid & 15;
  const int g     = tid >> 4;          // 16 groups x 4 tokens
  const int lane  = tid & 63;
  const int gbase = lane & 48;

  float biasr[8];
#pragma unroll
  for (int j = 0; j < 4; ++j) {
    biasr[j]     = bias[tx * 4 + j];
    biasr[4 + j] = bias[64 + tx * 4 + j];
  }

#pragma unroll
  for (int it = 0; it < 4; ++it) {
    const int tok = g * 4 + it;
    const float4 lo4 = *(const float4*)(logits + tok * 132 + tx * 4);
    const float4 hi4 = *(const float4*)(logits + tok * 132 + 64 + tx * 4);
    float sc[8], bal[8];
#pragma unroll
    for (int j = 0; j < 4; ++j) {
      sc[j]     = 1.f / (1.f + expf(-((const float*)&lo4)[j]));
      sc[4 + j] = 1.f / (1.f + expf(-((const float*)&hi4)[j]));
    }
#pragma unroll
    for (int j = 0; j < 8; ++j) bal[j] = sc[j] + biasr[j];

    float myw[TOPK];
    int   myid[TOPK];
    float prev = 0.f;
    int   flagged = 0;
#pragma unroll
    for (int r = 0; r < TOPK + 1; ++r) {
      float bv = bal[0];
      int   bi = tx * 4;
#pragma unroll
      for (int j = 1; j < 8; ++j) {
        const int ej = (j < 4) ? (tx * 4 + j) : (64 + tx * 4 + (j - 4));
        if (bal[j] > bv) { bv = bal[j]; bi = ej; }
      }
#pragma unroll
      for (int m = 1; m <= 8; m <<= 1) {
        const float ov = __shfl_xor(bv, m);
        const int   oi = __shfl_xor(bi, m);
        if (ov > bv || (ov == bv && oi < bi)) { bv = ov; bi = oi; }
      }
      if (r > 0 && (prev - bv) < MARGIN) flagged = 1;
      prev = bv;
      if (r < TOPK) {
        const int ls = (bi < 64) ? (bi >> 2) : ((bi - 64) >> 2);
        const int jt = (bi < 64) ? (bi & 3) : (4 + ((bi - 64) & 3));
        const float a0 = (jt & 1) ? sc[1] : sc[0];
        const float a1 = (jt & 1) ? sc[3] : sc[2];
        const float a2 = (jt & 1) ? sc[5] : sc[4];
        const float a3 = (jt & 1) ? sc[7] : sc[6];
        const float b0 = (jt & 2) ? a1 : a0;
        const float b1 = (jt & 2) ? a3 : a2;
        const float sv = (jt & 4) ? b1 : b0;
        const float sw = __shfl(sv, gbase | ls);
        myw[r]  = sw;
        myid[r] = bi;
#pragma unroll
        for (int j = 0; j < 8; ++j)
          if (tx == ls && j == jt) bal[j] = -INFINITY;
      }
    }

    if (tx == 0) {
      float den = 0.f;
#pragma unroll
      for (int r = 0; r < TOPK; ++r) den += fabsf(myw[r]);
      den = fmaxf(den, 1e-12f);
      const int t = t0 + tok;
      float4* wo = (float4*)(out_w + (size_t)t * TOPK);
      float4* io = (float4*)(out_i + (size_t)t * TOPK);
      wo[0] = make_float4(myw[0] / den, myw[1] / den, myw[2] / den, myw[3] / den);
      wo[1] = make_float4(myw[4] / den, myw[5] / den, myw[6] / den, myw[7] / den);
      io[0] = make_float4((float)myid[0], (float)myid[1], (float)myid[2], (float)myid[3]);
      io[1] = make_float4((float)myid[4], (float)myid[5], (float)myid[6], (float)myid[7]);
      if (flagged) atomicOr(&mask[t >> 5], 1u << (t & 31));
    }
  }
}

// ---------------- Compaction: bitmask -> ordered token list (deterministic) ----------------
__global__ __launch_bounds__(1024) void router_compact(
    const unsigned int* __restrict__ mask, int* __restrict__ cnt,
    int* __restrict__ flags, int nwords) {
  __shared__ int wsum[17];
  const int tid = threadIdx.x;
  unsigned int w = (tid < nwords) ? mask[tid] : 0u;
  const int c = __popc(w);
  const int lane = tid & 63;
  const int wv   = tid >> 6;
  int inc = c;
#pragma unroll
  for (int m = 1; m < 64; m <<= 1) {
    const int v = __shfl_up(inc, m);
    if (lane >= m) inc += v;
  }
  if (lane == 63) wsum[wv + 1] = inc;
  __syncthreads();
  if (tid == 0) {
    wsum[0] = 0;
    for (int i = 1; i <= 16; ++i) wsum[i] += wsum[i - 1];
    cnt[0] = wsum[16];
  }
  __syncthreads();
  int off = wsum[wv] + inc - c;
  while (w) {
    const int b = __ffs(w) - 1;
    w &= w - 1u;
    flags[off++] = tid * 32 + b;
  }
}

// ---------------- Pass 2: fp64 recompute, 4 tokens per block (grid-stride) ----------------
__global__ __launch_bounds__(256) void router_pass2(
    const float* __restrict__ x, const float* __restrict__ W,
    const float* __restrict__ bias,
    float* __restrict__ out_w, float* __restrict__ out_i,
    const int* __restrict__ cnt, const int* __restrict__ flags, int H) {
  __shared__ float  xs[4 * 4096];      // 64 KB
  __shared__ double red[4 * NE];

  const int tid = threadIdx.x;
  const int e   = tid & 127;
  const int h   = tid >> 7;
  const int count = cnt[0];

  for (int gidx = blockIdx.x; gidx * 4 < count; gidx += gridDim.x) {
    const int nt = min(4, count - gidx * 4);
    int toks[4];
#pragma unroll
    for (int t = 0; t < 4; ++t) toks[t] = flags[gidx * 4 + min(t, nt - 1)];

    __syncthreads();
#pragma unroll
    for (int t = 0; t < 4; ++t) {
      const float* xp = x + (size_t)toks[t] * H;
#pragma unroll
      for (int c = 0; c < 4; ++c) {
        const int fi = (c * 256 + tid) * 4;
        *(float4*)(xs + t * 4096 + fi) = *(const float4*)(xp + fi);
      }
    }
    __syncthreads();

    double a[4] = {0.0, 0.0, 0.0, 0.0};
    {
      const float* wp = W + (size_t)e * H + h * 2048;
      const float* xb = xs + h * 2048;
      for (int kk = 0; kk < 2048; kk += 4) {
        const float4 wv = *(const float4*)(wp + kk);
#pragma unroll
        for (int t = 0; t < 4; ++t) {
          const float4 xv = *(const float4*)(xb + t * 4096 + kk);
          a[t] = fma((double)xv.x, (double)wv.x, a[t]);
          a[t] = fma((double)xv.y, (double)wv.y, a[t]);
          a[t] = fma((double)xv.z, (double)wv.z, a[t]);
          a[t] = fma((double)xv.w, (double)wv.w, a[t]);
        }
      }
    }

    if (h == 1) {
#pragma unroll
      for (int t = 0; t < 4; ++t) red[t * NE + e] = a[t];
    }
    __syncthreads();
    if (h == 0) {
#pragma unroll
      for (int t = 0; t < 4; ++t)
        red[t * NE + e] = 1.0 / (1.0 + exp(-(a[t] + red[t * NE + e])));
    }
    __syncthreads();

    if (tid < 64) {
      const int l = tid;
      const double b0d = (double)bias[l];
      const double b1d = (double)bias[64 + l];
#pragma unroll
      for (int t = 0; t < 4; ++t) {
        const double s0 = red[t * NE + l];
        const double s1 = red[t * NE + 64 + l];
        double g0 = s0 + b0d;
        double g1 = s1 + b1d;
        double myw[TOPK]; int myid[TOPK];
#pragma unroll
        for (int r = 0; r < TOPK; ++r) {
          double bv; int bi;
          if (g1 > g0) { bv = g1; bi = 64 + l; } else { bv = g0; bi = l; }
#pragma unroll
          for (int m = 1; m <= 32; m <<= 1) {
            const double ov = __shfl_xor(bv, m);
            const int    oi = __shfl_xor(bi, m);
            if (ov > bv || (ov == bv && oi < bi)) { bv = ov; bi = oi; }
          }
          const int ls   = bi & 63;
          const int slot = bi >> 6;
          const double sv = slot ? s1 : s0;
          const double sw = __shfl(sv, ls);
          myw[r]  = sw;
          myid[r] = bi;
          if (l == ls) { if (slot) g1 = -INFINITY; else g0 = -INFINITY; }
        }
        if (l == 0 && t < nt) {
          double den = 0.0;
#pragma unroll
          for (int r = 0; r < TOPK; ++r) den += fabs(myw[r]);
          den = fmax(den, 1e-12);
          const int tok = toks[t];
#pragma unroll
          for (int r = 0; r < TOPK; ++r) {
            out_w[(size_t)tok * TOPK + r] = (float)(myw[r] / den);
            out_i[(size_t)tok * TOPK + r] = (float)myid[r];
          }
        }
      }
    }
  }
}

extern "C" void kernel_launch(void* const* d_in, const int* in_sizes, int n_in,
                              void* d_out, int out_size, void* d_ws, size_t ws_size,
                              hipStream_t stream) {
  const float* x    = (const float*)d_in[0];
  const float* W    = (const float*)d_in[1];
  const float* bias = (const float*)d_in[2];
  const int E = in_sizes[2];            // 128
  const int H = in_sizes[1] / E;        // 4096
  const int T = in_sizes[0] / H;        // 32768
  (void)E; (void)n_in; (void)ws_size; (void)out_size;

  float* out_w = (float*)d_out;
  float* out_i = out_w + (size_t)T * TOPK;

  // workspace layout (bytes): whi [1MB] | wlo [1MB] | mask [4KB] | cnt [16B] | flags
  char* ws = (char*)d_ws;
  _Float16* whi = (_Float16*)ws;
  _Float16* wlo = (_Float16*)(ws + (1 << 20));
  unsigned int* mask = (unsigned int*)(ws + (2 << 20));
  const int nwords = (T + 31) / 32;     // 1024
  int* cnt   = (int*)(ws + (2 << 20) + nwords * 4);
  int* flags = (int*)(ws + (2 << 20) + nwords * 4 + 16);

  hipMemsetAsync(mask, 0, (size_t)nwords * 4 + 16, stream);

  const int n4 = (E * H) / 4;           // 131072 float4s
  router_wsplit<<<dim3((n4 + 255) / 256), dim3(256), 0, stream>>>(W, whi, wlo, n4);
  router_pass1<<<dim3(T / 64), dim3(256), 0, stream>>>(x, whi, wlo, bias, out_w, out_i, mask, T, H);
  router_compact<<<dim3(1), dim3(1024), 0, stream>>>(mask, cnt, flags, nwords);
  router_pass2<<<dim3(2048), dim3(256), 0, stream>>>(x, W, bias, out_w, out_i, cnt, flags, H);
}

// Round 8
// 314.392 us; speedup vs baseline: 2.0784x; 2.0784x over previous
//
#include <hip/hip_runtime.h>
#include <math.h>

#define TOPK 8
#define NE   128
#define MARGIN 4e-5f

typedef _Float16 h8 __attribute__((ext_vector_type(8)));
typedef _Float16 h4 __attribute__((ext_vector_type(4)));
typedef float    f4 __attribute__((ext_vector_type(4)));

// byte address within a [row][64 halfs] LDS array (128 B row stride),
// XOR-swizzled so 16-lane column reads spread across banks.
__device__ __forceinline__ int swz(int row, int kb) {
  return row * 128 + (kb ^ ((row & 7) << 4));
}

#define GLOAD_LDS16(g, l)                                              \
  __builtin_amdgcn_global_load_lds(                                    \
      (const __attribute__((address_space(1))) void*)(g),              \
      (__attribute__((address_space(3))) void*)(l), 16, 0, 0)

// ---------------- Kernel 0: split W into fp16 hi + scaled lo ----------------
__global__ __launch_bounds__(256) void router_wsplit(
    const float* __restrict__ W, _Float16* __restrict__ whi,
    _Float16* __restrict__ wlo, int n4) {
  const int i = blockIdx.x * 256 + threadIdx.x;
  if (i < n4) {
    const float4 v = ((const float4*)W)[i];
    h4 hi, lo;
#pragma unroll
    for (int q = 0; q < 4; ++q) {
      const float vq = ((const float*)&v)[q];
      const _Float16 h = (_Float16)vq;
      hi[q] = h;
      lo[q] = (_Float16)((vq - (float)h) * 2048.0f);  // lo' = lo * 2^11
    }
    ((h4*)whi)[i] = hi;
    ((h4*)wlo)[i] = lo;
  }
}

// ---------------- Pass 1: split-fp16 MFMA GEMM + sigmoid + top-8 + flag ----------------
// 256 threads = 4 waves; block tile 64 tokens x 128 experts; BK=64.
// W staged via global_load_lds (linear dest, pre-swizzled source); x via 16 regs.
__global__ __launch_bounds__(256, 2) void router_pass1(
    const float* __restrict__ x,        // [T, H] fp32
    const _Float16* __restrict__ whi,   // [E, H] fp16
    const _Float16* __restrict__ wlo,   // [E, H] fp16 (x 2^11)
    const float* __restrict__ bias,
    float* __restrict__ out_w, float* __restrict__ out_i,
    unsigned int* __restrict__ mask, int T, int H) {
  __shared__ char lds[49152];
  // a_hi @0 (8KB: 64 rows x 128B), a_lo @8192, b_hi @16384 (16KB: 128 rows), b_lo @32768
  // epilogue reuse: logits fp32 [64][132] @0 (33.8 KB)

  const int tid = threadIdx.x;
  const int t0  = blockIdx.x * 64;
  const int l   = tid & 63;
  const int wv  = tid >> 6;
  const int wm  = wv & 1;              // token half (32)
  const int wn  = wv >> 1;             // expert half (64)

  const int xtok = tid >> 2, xc4 = tid & 3;     // x staging: row, col-group

  // W DMA: per-lane pre-swizzled source byte-offsets (k0-invariant).
  // Linear LDS offset o -> (row, kb) such that LDS[swz(row,kb)] = W[row][kb].
  int wsrc[4];
#pragma unroll
  for (int i = 0; i < 4; ++i) {
    const int o   = wv * 4096 + i * 1024 + l * 16;
    const int row = o >> 7;
    const int kb  = (o & 127) ^ ((row & 7) << 4);
    wsrc[i] = row * (H * 2) + kb;
  }
  char* const bhi_base = lds + 16384 + wv * 4096;   // wave-uniform DMA dest
  char* const blo_base = lds + 32768 + wv * 4096;

  const float* xbase = x + (size_t)(t0 + xtok) * H + xc4 * 4;

  f4 acc1[2][4], acc2[2][4];
#pragma unroll
  for (int mt = 0; mt < 2; ++mt)
#pragma unroll
    for (int nt = 0; nt < 4; ++nt) {
      acc1[mt][nt] = (f4)0.0f;
      acc2[mt][nt] = (f4)0.0f;
    }

  float4 px[4];
#pragma unroll
  for (int j = 0; j < 4; ++j) px[j] = *(const float4*)(xbase + j * 16);

  for (int k0 = 0; k0 < H; k0 += 64) {
    __syncthreads();                   // previous tile's LDS reads done
    // ---- issue W DMA (global -> LDS direct, no VGPRs) ----
    {
      const char* whb = (const char*)whi + (size_t)k0 * 2;
      const char* wlb = (const char*)wlo + (size_t)k0 * 2;
#pragma unroll
      for (int i = 0; i < 4; ++i) {
        GLOAD_LDS16(whb + wsrc[i], bhi_base + i * 1024);
        GLOAD_LDS16(wlb + wsrc[i], blo_base + i * 1024);
      }
    }
    // ---- x: convert staged regs to hi/lo fp16, write swizzled ----
#pragma unroll
    for (int j = 0; j < 4; ++j) {
      const float4 v = px[j];
      h4 hi, lo;
#pragma unroll
      for (int q = 0; q < 4; ++q) {
        const float vq = ((const float*)&v)[q];
        const _Float16 h = (_Float16)vq;
        hi[q] = h;
        lo[q] = (_Float16)((vq - (float)h) * 2048.0f);
      }
      const int kb = xc4 * 8 + j * 32;
      *(h4*)(lds +        swz(xtok, kb)) = hi;
      *(h4*)(lds + 8192 + swz(xtok, kb)) = lo;
    }
    // ---- prefetch next x tile ----
    if (k0 + 64 < H) {
#pragma unroll
      for (int j = 0; j < 4; ++j)
        px[j] = *(const float4*)(xbase + k0 + 64 + j * 16);
    }
    __syncthreads();                   // vmcnt(0) drain: DMA + px complete

    // ---- MFMA over two K=32 steps ----
#pragma unroll
    for (int ks = 0; ks < 2; ++ks) {
      const int kb = ks * 64 + ((l >> 4) * 16);
      h8 Ah[2], Al[2];
#pragma unroll
      for (int mt = 0; mt < 2; ++mt) {
        const int row = wm * 32 + mt * 16 + (l & 15);
        Ah[mt] = *(const h8*)(lds +        swz(row, kb));
        Al[mt] = *(const h8*)(lds + 8192 + swz(row, kb));
      }
#pragma unroll
      for (int nt = 0; nt < 4; ++nt) {
        const int er = wn * 64 + nt * 16 + (l & 15);
        const h8 Bh = *(const h8*)(lds + 16384 + swz(er, kb));
        const h8 Bl = *(const h8*)(lds + 32768 + swz(er, kb));
#pragma unroll
        for (int mt = 0; mt < 2; ++mt) {
          acc1[mt][nt] = __builtin_amdgcn_mfma_f32_16x16x32_f16(Ah[mt], Bh, acc1[mt][nt], 0, 0, 0);
          acc2[mt][nt] = __builtin_amdgcn_mfma_f32_16x16x32_f16(Ah[mt], Bl, acc2[mt][nt], 0, 0, 0);
          acc2[mt][nt] = __builtin_amdgcn_mfma_f32_16x16x32_f16(Al[mt], Bh, acc2[mt][nt], 0, 0, 0);
        }
      }
    }
  }

  // ---- dump logits to LDS (C/D layout: col=lane&15, row=(lane>>4)*4+r) ----
  __syncthreads();
  float* logits = (float*)lds;
#pragma unroll
  for (int mt = 0; mt < 2; ++mt)
#pragma unroll
    for (int nt = 0; nt < 4; ++nt)
#pragma unroll
      for (int r = 0; r < 4; ++r) {
        const int row = wm * 32 + mt * 16 + (l >> 4) * 4 + r;
        const int col = wn * 64 + nt * 16 + (l & 15);
        logits[row * 132 + col] = acc1[mt][nt][r] + acc2[mt][nt][r] * (1.0f / 2048.0f);
      }
  __syncthreads();

  // ---- epilogue: sigmoid, top-8 across 16-lane groups, flag near-ties ----
  const int tx    = tid & 15;
  const int g     = tid >> 4;          // 16 groups x 4 tokens
  const int lane  = tid & 63;
  const int gbase = lane & 48;

  float biasr[8];
#pragma unroll
  for (int j = 0; j < 4; ++j) {
    biasr[j]     = bias[tx * 4 + j];
    biasr[4 + j] = bias[64 + tx * 4 + j];
  }

#pragma unroll
  for (int it = 0; it < 4; ++it) {
    const int tok = g * 4 + it;
    const float4 lo4 = *(const float4*)(logits + tok * 132 + tx * 4);
    const float4 hi4 = *(const float4*)(logits + tok * 132 + 64 + tx * 4);
    float sc[8], bal[8];
#pragma unroll
    for (int j = 0; j < 4; ++j) {
      sc[j]     = 1.f / (1.f + expf(-((const float*)&lo4)[j]));
      sc[4 + j] = 1.f / (1.f + expf(-((const float*)&hi4)[j]));
    }
#pragma unroll
    for (int j = 0; j < 8; ++j) bal[j] = sc[j] + biasr[j];

    float myw[TOPK];
    int   myid[TOPK];
    float prev = 0.f;
    int   flagged = 0;
#pragma unroll
    for (int r = 0; r < TOPK + 1; ++r) {
      float bv = bal[0];
      int   bi = tx * 4;
#pragma unroll
      for (int j = 1; j < 8; ++j) {
        const int ej = (j < 4) ? (tx * 4 + j) : (64 + tx * 4 + (j - 4));
        if (bal[j] > bv) { bv = bal[j]; bi = ej; }
      }
#pragma unroll
      for (int m = 1; m <= 8; m <<= 1) {
        const float ov = __shfl_xor(bv, m);
        const int   oi = __shfl_xor(bi, m);
        if (ov > bv || (ov == bv && oi < bi)) { bv = ov; bi = oi; }
      }
      if (r > 0 && (prev - bv) < MARGIN) flagged = 1;
      prev = bv;
      if (r < TOPK) {
        const int ls = (bi < 64) ? (bi >> 2) : ((bi - 64) >> 2);
        const int jt = (bi < 64) ? (bi & 3) : (4 + ((bi - 64) & 3));
        const float a0 = (jt & 1) ? sc[1] : sc[0];
        const float a1 = (jt & 1) ? sc[3] : sc[2];
        const float a2 = (jt & 1) ? sc[5] : sc[4];
        const float a3 = (jt & 1) ? sc[7] : sc[6];
        const float b0 = (jt & 2) ? a1 : a0;
        const float b1 = (jt & 2) ? a3 : a2;
        const float sv = (jt & 4) ? b1 : b0;
        const float sw = __shfl(sv, gbase | ls);
        myw[r]  = sw;
        myid[r] = bi;
#pragma unroll
        for (int j = 0; j < 8; ++j)
          if (tx == ls && j == jt) bal[j] = -INFINITY;
      }
    }

    if (tx == 0) {
      float den = 0.f;
#pragma unroll
      for (int r = 0; r < TOPK; ++r) den += fabsf(myw[r]);
      den = fmaxf(den, 1e-12f);
      const int t = t0 + tok;
      float4* wo = (float4*)(out_w + (size_t)t * TOPK);
      float4* io = (float4*)(out_i + (size_t)t * TOPK);
      wo[0] = make_float4(myw[0] / den, myw[1] / den, myw[2] / den, myw[3] / den);
      wo[1] = make_float4(myw[4] / den, myw[5] / den, myw[6] / den, myw[7] / den);
      io[0] = make_float4((float)myid[0], (float)myid[1], (float)myid[2], (float)myid[3]);
      io[1] = make_float4((float)myid[4], (float)myid[5], (float)myid[6], (float)myid[7]);
      if (flagged) atomicOr(&mask[t >> 5], 1u << (t & 31));
    }
  }
}

// ---------------- Compaction: bitmask -> ordered token list (deterministic) ----------------
__global__ __launch_bounds__(1024) void router_compact(
    const unsigned int* __restrict__ mask, int* __restrict__ cnt,
    int* __restrict__ flags, int nwords) {
  __shared__ int wsum[17];
  const int tid = threadIdx.x;
  unsigned int w = (tid < nwords) ? mask[tid] : 0u;
  const int c = __popc(w);
  const int lane = tid & 63;
  const int wv   = tid >> 6;
  int inc = c;
#pragma unroll
  for (int m = 1; m < 64; m <<= 1) {
    const int v = __shfl_up(inc, m);
    if (lane >= m) inc += v;
  }
  if (lane == 63) wsum[wv + 1] = inc;
  __syncthreads();
  if (tid == 0) {
    wsum[0] = 0;
    for (int i = 1; i <= 16; ++i) wsum[i] += wsum[i - 1];
    cnt[0] = wsum[16];
  }
  __syncthreads();
  int off = wsum[wv] + inc - c;
  while (w) {
    const int b = __ffs(w) - 1;
    w &= w - 1u;
    flags[off++] = tid * 32 + b;
  }
}

// ---------------- Pass 2: fp64 recompute, 4 tokens per block (grid-stride) ----------------
__global__ __launch_bounds__(256) void router_pass2(
    const float* __restrict__ x, const float* __restrict__ W,
    const float* __restrict__ bias,
    float* __restrict__ out_w, float* __restrict__ out_i,
    const int* __restrict__ cnt, const int* __restrict__ flags, int H) {
  __shared__ float  xs[4 * 4096];      // 64 KB
  __shared__ double red[4 * NE];

  const int tid = threadIdx.x;
  const int e   = tid & 127;
  const int h   = tid >> 7;
  const int count = cnt[0];

  for (int gidx = blockIdx.x; gidx * 4 < count; gidx += gridDim.x) {
    const int nt = min(4, count - gidx * 4);
    int toks[4];
#pragma unroll
    for (int t = 0; t < 4; ++t) toks[t] = flags[gidx * 4 + min(t, nt - 1)];

    __syncthreads();
#pragma unroll
    for (int t = 0; t < 4; ++t) {
      const float* xp = x + (size_t)toks[t] * H;
#pragma unroll
      for (int c = 0; c < 4; ++c) {
        const int fi = (c * 256 + tid) * 4;
        *(float4*)(xs + t * 4096 + fi) = *(const float4*)(xp + fi);
      }
    }
    __syncthreads();

    double a[4] = {0.0, 0.0, 0.0, 0.0};
    {
      const float* wp = W + (size_t)e * H + h * 2048;
      const float* xb = xs + h * 2048;
      for (int kk = 0; kk < 2048; kk += 4) {
        const float4 wv = *(const float4*)(wp + kk);
#pragma unroll
        for (int t = 0; t < 4; ++t) {
          const float4 xv = *(const float4*)(xb + t * 4096 + kk);
          a[t] = fma((double)xv.x, (double)wv.x, a[t]);
          a[t] = fma((double)xv.y, (double)wv.y, a[t]);
          a[t] = fma((double)xv.z, (double)wv.z, a[t]);
          a[t] = fma((double)xv.w, (double)wv.w, a[t]);
        }
      }
    }

    if (h == 1) {
#pragma unroll
      for (int t = 0; t < 4; ++t) red[t * NE + e] = a[t];
    }
    __syncthreads();
    if (h == 0) {
#pragma unroll
      for (int t = 0; t < 4; ++t)
        red[t * NE + e] = 1.0 / (1.0 + exp(-(a[t] + red[t * NE + e])));
    }
    __syncthreads();

    if (tid < 64) {
      const int l = tid;
      const double b0d = (double)bias[l];
      const double b1d = (double)bias[64 + l];
#pragma unroll
      for (int t = 0; t < 4; ++t) {
        const double s0 = red[t * NE + l];
        const double s1 = red[t * NE + 64 + l];
        double g0 = s0 + b0d;
        double g1 = s1 + b1d;
        double myw[TOPK]; int myid[TOPK];
#pragma unroll
        for (int r = 0; r < TOPK; ++r) {
          double bv; int bi;
          if (g1 > g0) { bv = g1; bi = 64 + l; } else { bv = g0; bi = l; }
#pragma unroll
          for (int m = 1; m <= 32; m <<= 1) {
            const double ov = __shfl_xor(bv, m);
            const int    oi = __shfl_xor(bi, m);
            if (ov > bv || (ov == bv && oi < bi)) { bv = ov; bi = oi; }
          }
          const int ls   = bi & 63;
          const int slot = bi >> 6;
          const double sv = slot ? s1 : s0;
          const double sw = __shfl(sv, ls);
          myw[r]  = sw;
          myid[r] = bi;
          if (l == ls) { if (slot) g1 = -INFINITY; else g0 = -INFINITY; }
        }
        if (l == 0 && t < nt) {
          double den = 0.0;
#pragma unroll
          for (int r = 0; r < TOPK; ++r) den += fabs(myw[r]);
          den = fmax(den, 1e-12);
          const int tok = toks[t];
#pragma unroll
          for (int r = 0; r < TOPK; ++r) {
            out_w[(size_t)tok * TOPK + r] = (float)(myw[r] / den);
            out_i[(size_t)tok * TOPK + r] = (float)myid[r];
          }
        }
      }
    }
  }
}

extern "C" void kernel_launch(void* const* d_in, const int* in_sizes, int n_in,
                              void* d_out, int out_size, void* d_ws, size_t ws_size,
                              hipStream_t stream) {
  const float* x    = (const float*)d_in[0];
  const float* W    = (const float*)d_in[1];
  const float* bias = (const float*)d_in[2];
  const int E = in_sizes[2];            // 128
  const int H = in_sizes[1] / E;        // 4096
  const int T = in_sizes[0] / H;        // 32768
  (void)E; (void)n_in; (void)ws_size; (void)out_size;

  float* out_w = (float*)d_out;
  float* out_i = out_w + (size_t)T * TOPK;

  // workspace layout (bytes): whi [1MB] | wlo [1MB] | mask [4KB] | cnt [16B] | flags
  char* ws = (char*)d_ws;
  _Float16* whi = (_Float16*)ws;
  _Float16* wlo = (_Float16*)(ws + (1 << 20));
  unsigned int* mask = (unsigned int*)(ws + (2 << 20));
  const int nwords = (T + 31) / 32;     // 1024
  int* cnt   = (int*)(ws + (2 << 20) + nwords * 4);
  int* flags = (int*)(ws + (2 << 20) + nwords * 4 + 16);

  hipMemsetAsync(mask, 0, (size_t)nwords * 4 + 16, stream);

  const int n4 = (E * H) / 4;           // 131072 float4s
  router_wsplit<<<dim3((n4 + 255) / 256), dim3(256), 0, stream>>>(W, whi, wlo, n4);
  router_pass1<<<dim3(T / 64), dim3(256), 0, stream>>>(x, whi, wlo, bias, out_w, out_i, mask, T, H);
  router_compact<<<dim3(1), dim3(1024), 0, stream>>>(mask, cnt, flags, nwords);
  router_pass2<<<dim3(2048), dim3(256), 0, stream>>>(x, W, bias, out_w, out_i, cnt, flags, H);
}

// Round 9
// 310.817 us; speedup vs baseline: 2.1023x; 1.0115x over previous
//
#include <hip/hip_runtime.h>
#include <math.h>

#define TOPK 8
#define NE   128
#define MARGIN 4e-5f

typedef _Float16 h8 __attribute__((ext_vector_type(8)));
typedef _Float16 h4 __attribute__((ext_vector_type(4)));
typedef float    f4 __attribute__((ext_vector_type(4)));

// byte address within a [row][64 halfs] LDS array (128 B row stride),
// XOR-swizzled so 16-lane column reads spread across banks.
__device__ __forceinline__ int swz(int row, int kb) {
  return row * 128 + (kb ^ ((row & 7) << 4));
}

#define GLOAD_LDS16(g, l)                                              \
  __builtin_amdgcn_global_load_lds(                                    \
      (const __attribute__((address_space(1))) void*)(g),              \
      (__attribute__((address_space(3))) void*)(l), 16, 0, 0)

// ---------------- Kernel 0: split W into fp16 hi + scaled lo ----------------
__global__ __launch_bounds__(256) void router_wsplit(
    const float* __restrict__ W, _Float16* __restrict__ whi,
    _Float16* __restrict__ wlo, int n4) {
  const int i = blockIdx.x * 256 + threadIdx.x;
  if (i < n4) {
    const float4 v = ((const float4*)W)[i];
    h4 hi, lo;
#pragma unroll
    for (int q = 0; q < 4; ++q) {
      const float vq = ((const float*)&v)[q];
      const _Float16 h = (_Float16)vq;
      hi[q] = h;
      lo[q] = (_Float16)((vq - (float)h) * 2048.0f);  // lo' = lo * 2^11
    }
    ((h4*)whi)[i] = hi;
    ((h4*)wlo)[i] = lo;
  }
}

// ---------------- Pass 1: split-fp16 MFMA GEMM + sigmoid + top-8 + flag ----------------
// 256 threads = 4 waves; block tile 64 tokens x 128 experts; BK=64; 3 blocks/CU.
// W staged via global_load_lds (linear dest, pre-swizzled source); x prefetched
// in registers with the issue AFTER barrier2 so the HBM latency hides under MFMA.
__global__ __launch_bounds__(256, 3) void router_pass1(
    const float* __restrict__ x,        // [T, H] fp32
    const _Float16* __restrict__ whi,   // [E, H] fp16
    const _Float16* __restrict__ wlo,   // [E, H] fp16 (x 2^11)
    const float* __restrict__ bias,
    float* __restrict__ out_w, float* __restrict__ out_i,
    unsigned int* __restrict__ mask, int T, int H) {
  __shared__ char lds[49152];
  // a_hi @0 (8KB: 64 rows x 128B), a_lo @8192, b_hi @16384 (16KB: 128 rows), b_lo @32768
  // epilogue reuse: logits fp32 [64][132] @0 (33.8 KB)

  const int tid = threadIdx.x;
  const int t0  = blockIdx.x * 64;
  const int l   = tid & 63;
  const int wv  = tid >> 6;
  const int wm  = wv & 1;              // token half (32)
  const int wn  = wv >> 1;             // expert half (64)

  const int xtok = tid >> 2, xc4 = tid & 3;     // x staging: row, col-group

  // W DMA: per-lane pre-swizzled source byte-offsets (k0-invariant).
  int wsrc[4];
#pragma unroll
  for (int i = 0; i < 4; ++i) {
    const int o   = wv * 4096 + i * 1024 + l * 16;
    const int row = o >> 7;
    const int kb  = (o & 127) ^ ((row & 7) << 4);
    wsrc[i] = row * (H * 2) + kb;
  }
  char* const bhi_base = lds + 16384 + wv * 4096;   // wave-uniform DMA dest
  char* const blo_base = lds + 32768 + wv * 4096;

  const float* xbase = x + (size_t)(t0 + xtok) * H + xc4 * 4;

  f4 acc1[2][4], acc2[2][4];
#pragma unroll
  for (int mt = 0; mt < 2; ++mt)
#pragma unroll
    for (int nt = 0; nt < 4; ++nt) {
      acc1[mt][nt] = (f4)0.0f;
      acc2[mt][nt] = (f4)0.0f;
    }

  float4 px[4];
#pragma unroll
  for (int j = 0; j < 4; ++j) px[j] = *(const float4*)(xbase + j * 16);

  for (int k0 = 0; k0 < H; k0 += 64) {
    __syncthreads();                   // barrier1: prev LDS reads done; drains px
    // ---- issue W DMA (global -> LDS direct, no VGPRs) ----
    {
      const char* whb = (const char*)whi + (size_t)k0 * 2;
      const char* wlb = (const char*)wlo + (size_t)k0 * 2;
#pragma unroll
      for (int i = 0; i < 4; ++i) {
        GLOAD_LDS16(whb + wsrc[i], bhi_base + i * 1024);
        GLOAD_LDS16(wlb + wsrc[i], blo_base + i * 1024);
      }
    }
    // ---- x: convert staged regs to hi/lo fp16, write swizzled ----
#pragma unroll
    for (int j = 0; j < 4; ++j) {
      const float4 v = px[j];
      h4 hi, lo;
#pragma unroll
      for (int q = 0; q < 4; ++q) {
        const float vq = ((const float*)&v)[q];
        const _Float16 h = (_Float16)vq;
        hi[q] = h;
        lo[q] = (_Float16)((vq - (float)h) * 2048.0f);
      }
      const int kb = xc4 * 8 + j * 32;
      *(h4*)(lds +        swz(xtok, kb)) = hi;
      *(h4*)(lds + 8192 + swz(xtok, kb)) = lo;
    }
    __syncthreads();                   // barrier2: drains W DMA; LDS tile ready

    // ---- issue next x tile NOW: latency hides under the MFMA phase ----
    if (k0 + 64 < H) {
#pragma unroll
      for (int j = 0; j < 4; ++j)
        px[j] = *(const float4*)(xbase + k0 + 64 + j * 16);
    }

    // ---- MFMA over two K=32 steps ----
#pragma unroll
    for (int ks = 0; ks < 2; ++ks) {
      const int kb = ks * 64 + ((l >> 4) * 16);
      h8 Ah[2], Al[2];
#pragma unroll
      for (int mt = 0; mt < 2; ++mt) {
        const int row = wm * 32 + mt * 16 + (l & 15);
        Ah[mt] = *(const h8*)(lds +        swz(row, kb));
        Al[mt] = *(const h8*)(lds + 8192 + swz(row, kb));
      }
#pragma unroll
      for (int nt = 0; nt < 4; ++nt) {
        const int er = wn * 64 + nt * 16 + (l & 15);
        const h8 Bh = *(const h8*)(lds + 16384 + swz(er, kb));
        const h8 Bl = *(const h8*)(lds + 32768 + swz(er, kb));
#pragma unroll
        for (int mt = 0; mt < 2; ++mt) {
          acc1[mt][nt] = __builtin_amdgcn_mfma_f32_16x16x32_f16(Ah[mt], Bh, acc1[mt][nt], 0, 0, 0);
          acc2[mt][nt] = __builtin_amdgcn_mfma_f32_16x16x32_f16(Ah[mt], Bl, acc2[mt][nt], 0, 0, 0);
          acc2[mt][nt] = __builtin_amdgcn_mfma_f32_16x16x32_f16(Al[mt], Bh, acc2[mt][nt], 0, 0, 0);
        }
      }
    }
  }

  // ---- dump logits to LDS (C/D layout: col=lane&15, row=(lane>>4)*4+r) ----
  __syncthreads();
  float* logits = (float*)lds;
#pragma unroll
  for (int mt = 0; mt < 2; ++mt)
#pragma unroll
    for (int nt = 0; nt < 4; ++nt)
#pragma unroll
      for (int r = 0; r < 4; ++r) {
        const int row = wm * 32 + mt * 16 + (l >> 4) * 4 + r;
        const int col = wn * 64 + nt * 16 + (l & 15);
        logits[row * 132 + col] = acc1[mt][nt][r] + acc2[mt][nt][r] * (1.0f / 2048.0f);
      }
  __syncthreads();

  // ---- epilogue: sigmoid, top-8 across 16-lane groups, flag near-ties ----
  const int tx    = tid & 15;
  const int g     = tid >> 4;          // 16 groups x 4 tokens
  const int lane  = tid & 63;
  const int gbase = lane & 48;

  float biasr[8];
#pragma unroll
  for (int j = 0; j < 4; ++j) {
    biasr[j]     = bias[tx * 4 + j];
    biasr[4 + j] = bias[64 + tx * 4 + j];
  }

#pragma unroll
  for (int it = 0; it < 4; ++it) {
    const int tok = g * 4 + it;
    const float4 lo4 = *(const float4*)(logits + tok * 132 + tx * 4);
    const float4 hi4 = *(const float4*)(logits + tok * 132 + 64 + tx * 4);
    float sc[8], bal[8];
#pragma unroll
    for (int j = 0; j < 4; ++j) {
      sc[j]     = 1.f / (1.f + expf(-((const float*)&lo4)[j]));
      sc[4 + j] = 1.f / (1.f + expf(-((const float*)&hi4)[j]));
    }
#pragma unroll
    for (int j = 0; j < 8; ++j) bal[j] = sc[j] + biasr[j];

    float myw[TOPK];
    int   myid[TOPK];
    float prev = 0.f;
    int   flagged = 0;
#pragma unroll
    for (int r = 0; r < TOPK + 1; ++r) {
      float bv = bal[0];
      int   bi = tx * 4;
#pragma unroll
      for (int j = 1; j < 8; ++j) {
        const int ej = (j < 4) ? (tx * 4 + j) : (64 + tx * 4 + (j - 4));
        if (bal[j] > bv) { bv = bal[j]; bi = ej; }
      }
#pragma unroll
      for (int m = 1; m <= 8; m <<= 1) {
        const float ov = __shfl_xor(bv, m);
        const int   oi = __shfl_xor(bi, m);
        if (ov > bv || (ov == bv && oi < bi)) { bv = ov; bi = oi; }
      }
      if (r > 0 && (prev - bv) < MARGIN) flagged = 1;
      prev = bv;
      if (r < TOPK) {
        const int ls = (bi < 64) ? (bi >> 2) : ((bi - 64) >> 2);
        const int jt = (bi < 64) ? (bi & 3) : (4 + ((bi - 64) & 3));
        const float a0 = (jt & 1) ? sc[1] : sc[0];
        const float a1 = (jt & 1) ? sc[3] : sc[2];
        const float a2 = (jt & 1) ? sc[5] : sc[4];
        const float a3 = (jt & 1) ? sc[7] : sc[6];
        const float b0 = (jt & 2) ? a1 : a0;
        const float b1 = (jt & 2) ? a3 : a2;
        const float sv = (jt & 4) ? b1 : b0;
        const float sw = __shfl(sv, gbase | ls);
        myw[r]  = sw;
        myid[r] = bi;
#pragma unroll
        for (int j = 0; j < 8; ++j)
          if (tx == ls && j == jt) bal[j] = -INFINITY;
      }
    }

    if (tx == 0) {
      float den = 0.f;
#pragma unroll
      for (int r = 0; r < TOPK; ++r) den += fabsf(myw[r]);
      den = fmaxf(den, 1e-12f);
      const int t = t0 + tok;
      float4* wo = (float4*)(out_w + (size_t)t * TOPK);
      float4* io = (float4*)(out_i + (size_t)t * TOPK);
      wo[0] = make_float4(myw[0] / den, myw[1] / den, myw[2] / den, myw[3] / den);
      wo[1] = make_float4(myw[4] / den, myw[5] / den, myw[6] / den, myw[7] / den);
      io[0] = make_float4((float)myid[0], (float)myid[1], (float)myid[2], (float)myid[3]);
      io[1] = make_float4((float)myid[4], (float)myid[5], (float)myid[6], (float)myid[7]);
      if (flagged) atomicOr(&mask[t >> 5], 1u << (t & 31));
    }
  }
}

// ---------------- Compaction: bitmask -> ordered token list (deterministic) ----------------
__global__ __launch_bounds__(1024) void router_compact(
    const unsigned int* __restrict__ mask, int* __restrict__ cnt,
    int* __restrict__ flags, int nwords) {
  __shared__ int wsum[17];
  const int tid = threadIdx.x;
  unsigned int w = (tid < nwords) ? mask[tid] : 0u;
  const int c = __popc(w);
  const int lane = tid & 63;
  const int wv   = tid >> 6;
  int inc = c;
#pragma unroll
  for (int m = 1; m < 64; m <<= 1) {
    const int v = __shfl_up(inc, m);
    if (lane >= m) inc += v;
  }
  if (lane == 63) wsum[wv + 1] = inc;
  __syncthreads();
  if (tid == 0) {
    wsum[0] = 0;
    for (int i = 1; i <= 16; ++i) wsum[i] += wsum[i - 1];
    cnt[0] = wsum[16];
  }
  __syncthreads();
  int off = wsum[wv] + inc - c;
  while (w) {
    const int b = __ffs(w) - 1;
    w &= w - 1u;
    flags[off++] = tid * 32 + b;
  }
}

// ---------------- Pass 2: fp64 recompute, 4 tokens per block (grid-stride) ----------------
__global__ __launch_bounds__(256) void router_pass2(
    const float* __restrict__ x, const float* __restrict__ W,
    const float* __restrict__ bias,
    float* __restrict__ out_w, float* __restrict__ out_i,
    const int* __restrict__ cnt, const int* __restrict__ flags, int H) {
  __shared__ float  xs[4 * 4096];      // 64 KB
  __shared__ double red[4 * NE];

  const int tid = threadIdx.x;
  const int e   = tid & 127;
  const int h   = tid >> 7;
  const int count = cnt[0];

  for (int gidx = blockIdx.x; gidx * 4 < count; gidx += gridDim.x) {
    const int nt = min(4, count - gidx * 4);
    int toks[4];
#pragma unroll
    for (int t = 0; t < 4; ++t) toks[t] = flags[gidx * 4 + min(t, nt - 1)];

    __syncthreads();
#pragma unroll
    for (int t = 0; t < 4; ++t) {
      const float* xp = x + (size_t)toks[t] * H;
#pragma unroll
      for (int c = 0; c < 4; ++c) {
        const int fi = (c * 256 + tid) * 4;
        *(float4*)(xs + t * 4096 + fi) = *(const float4*)(xp + fi);
      }
    }
    __syncthreads();

    double a[4] = {0.0, 0.0, 0.0, 0.0};
    {
      const float* wp = W + (size_t)e * H + h * 2048;
      const float* xb = xs + h * 2048;
      for (int kk = 0; kk < 2048; kk += 4) {
        const float4 wv = *(const float4*)(wp + kk);
#pragma unroll
        for (int t = 0; t < 4; ++t) {
          const float4 xv = *(const float4*)(xb + t * 4096 + kk);
          a[t] = fma((double)xv.x, (double)wv.x, a[t]);
          a[t] = fma((double)xv.y, (double)wv.y, a[t]);
          a[t] = fma((double)xv.z, (double)wv.z, a[t]);
          a[t] = fma((double)xv.w, (double)wv.w, a[t]);
        }
      }
    }

    if (h == 1) {
#pragma unroll
      for (int t = 0; t < 4; ++t) red[t * NE + e] = a[t];
    }
    __syncthreads();
    if (h == 0) {
#pragma unroll
      for (int t = 0; t < 4; ++t)
        red[t * NE + e] = 1.0 / (1.0 + exp(-(a[t] + red[t * NE + e])));
    }
    __syncthreads();

    if (tid < 64) {
      const int l = tid;
      const double b0d = (double)bias[l];
      const double b1d = (double)bias[64 + l];
#pragma unroll
      for (int t = 0; t < 4; ++t) {
        const double s0 = red[t * NE + l];
        const double s1 = red[t * NE + 64 + l];
        double g0 = s0 + b0d;
        double g1 = s1 + b1d;
        double myw[TOPK]; int myid[TOPK];
#pragma unroll
        for (int r = 0; r < TOPK; ++r) {
          double bv; int bi;
          if (g1 > g0) { bv = g1; bi = 64 + l; } else { bv = g0; bi = l; }
#pragma unroll
          for (int m = 1; m <= 32; m <<= 1) {
            const double ov = __shfl_xor(bv, m);
            const int    oi = __shfl_xor(bi, m);
            if (ov > bv || (ov == bv && oi < bi)) { bv = ov; bi = oi; }
          }
          const int ls   = bi & 63;
          const int slot = bi >> 6;
          const double sv = slot ? s1 : s0;
          const double sw = __shfl(sv, ls);
          myw[r]  = sw;
          myid[r] = bi;
          if (l == ls) { if (slot) g1 = -INFINITY; else g0 = -INFINITY; }
        }
        if (l == 0 && t < nt) {
          double den = 0.0;
#pragma unroll
          for (int r = 0; r < TOPK; ++r) den += fabs(myw[r]);
          den = fmax(den, 1e-12);
          const int tok = toks[t];
#pragma unroll
          for (int r = 0; r < TOPK; ++r) {
            out_w[(size_t)tok * TOPK + r] = (float)(myw[r] / den);
            out_i[(size_t)tok * TOPK + r] = (float)myid[r];
          }
        }
      }
    }
  }
}

extern "C" void kernel_launch(void* const* d_in, const int* in_sizes, int n_in,
                              void* d_out, int out_size, void* d_ws, size_t ws_size,
                              hipStream_t stream) {
  const float* x    = (const float*)d_in[0];
  const float* W    = (const float*)d_in[1];
  const float* bias = (const float*)d_in[2];
  const int E = in_sizes[2];            // 128
  const int H = in_sizes[1] / E;        // 4096
  const int T = in_sizes[0] / H;        // 32768
  (void)E; (void)n_in; (void)ws_size; (void)out_size;

  float* out_w = (float*)d_out;
  float* out_i = out_w + (size_t)T * TOPK;

  // workspace layout (bytes): whi [1MB] | wlo [1MB] | mask [4KB] | cnt [16B] | flags
  char* ws = (char*)d_ws;
  _Float16* whi = (_Float16*)ws;
  _Float16* wlo = (_Float16*)(ws + (1 << 20));
  unsigned int* mask = (unsigned int*)(ws + (2 << 20));
  const int nwords = (T + 31) / 32;     // 1024
  int* cnt   = (int*)(ws + (2 << 20) + nwords * 4);
  int* flags = (int*)(ws + (2 << 20) + nwords * 4 + 16);

  hipMemsetAsync(mask, 0, (size_t)nwords * 4 + 16, stream);

  const int n4 = (E * H) / 4;           // 131072 float4s
  router_wsplit<<<dim3((n4 + 255) / 256), dim3(256), 0, stream>>>(W, whi, wlo, n4);
  router_pass1<<<dim3(T / 64), dim3(256), 0, stream>>>(x, whi, wlo, bias, out_w, out_i, mask, T, H);
  router_compact<<<dim3(1), dim3(1024), 0, stream>>>(mask, cnt, flags, nwords);
  router_pass2<<<dim3(2048), dim3(256), 0, stream>>>(x, W, bias, out_w, out_i, cnt, flags, H);
}